// Round 10
// baseline (103.522 us; speedup 1.0000x reference)
//
#include <hip/hip_runtime.h>
#include <hip/hip_fp16.h>

// B=16384 samples, F=256 features, T=512 trees, D=7 levels below root, C=4 outputs
#define BB 16384
#define FF 256
#define TT 512
#define DD 7

// Tables: R1 covers levels (1,2), R3 (3,4), R5 (5,6) as 16B two-level records;
// N7 = level-7 (feat,bias); LP = fp16x4 leaf PAIRS (16B) indexed by p7.
constexpr int NR1 = TT * 2;      // 1024
constexpr int NR3 = TT * 8;      // 4096  (exactly 64 KB -> fits in LDS!)
constexpr int NR5 = TT * 32;     // 16384
constexpr int NN7 = TT * 128;    // 65536 (also LP count)
constexpr int NTOT = NR1 + NR3 + NR5 + NN7 + NN7;

constexpr size_t OFF_R3   = (size_t)NR1 * 16;
constexpr size_t OFF_R5   = OFF_R3 + (size_t)NR3 * 16;
constexpr size_t OFF_N7   = OFF_R5 + (size_t)NR5 * 16;
constexpr size_t OFF_LP   = OFF_N7 + (size_t)NN7 * 8;
constexpr size_t OFF_PART = OFF_LP + (size_t)NN7 * 16;
constexpr size_t WS_NEED  = OFF_PART + (size_t)2 * BB * 4 * sizeof(float);

__global__ void pack_kernel(const int* __restrict__ nf, const float* __restrict__ bf,
                            const float4* __restrict__ leaf4,
                            int4* __restrict__ R1, int4* __restrict__ R3,
                            int4* __restrict__ R5, int2* __restrict__ N7,
                            uint4* __restrict__ LP) {
    const int i = blockIdx.x * 256 + threadIdx.x;
    if (i < NR1) {                       // level-1 node i; level-2 children 2i,2i+1
        const int e0 = i, eC = 2 * TT + 2 * i;
        const int fp = (nf[e0] & 255) | ((nf[eC] & 255) << 8) | ((nf[eC + 1] & 255) << 16);
        R1[i] = make_int4(fp, __float_as_int(bf[e0]),
                          __float_as_int(bf[eC]), __float_as_int(bf[eC + 1]));
    } else if (i < NR1 + NR3) {
        const int r = i - NR1;
        const int e0 = 6 * TT + r, eC = 14 * TT + 2 * r;
        const int fp = (nf[e0] & 255) | ((nf[eC] & 255) << 8) | ((nf[eC + 1] & 255) << 16);
        R3[r] = make_int4(fp, __float_as_int(bf[e0]),
                          __float_as_int(bf[eC]), __float_as_int(bf[eC + 1]));
    } else if (i < NR1 + NR3 + NR5) {
        const int r = i - NR1 - NR3;
        const int e0 = 30 * TT + r, eC = 62 * TT + 2 * r;
        const int fp = (nf[e0] & 255) | ((nf[eC] & 255) << 8) | ((nf[eC + 1] & 255) << 16);
        R5[r] = make_int4(fp, __float_as_int(bf[e0]),
                          __float_as_int(bf[eC]), __float_as_int(bf[eC + 1]));
    } else if (i < NR1 + NR3 + NR5 + NN7) {
        const int r = i - NR1 - NR3 - NR5;
        const int e = 126 * TT + r;
        N7[r] = make_int2(nf[e] & 255, __float_as_int(bf[e]));
    } else if (i < NTOT) {
        const int j = i - NR1 - NR3 - NR5 - NN7;   // leaf-pair id: leaves 2j, 2j+1
        const float4 l0 = leaf4[2 * j], l1 = leaf4[2 * j + 1];
        const __half2 a = __floats2half2_rn(l0.x, l0.y), b = __floats2half2_rn(l0.z, l0.w);
        const __half2 c = __floats2half2_rn(l1.x, l1.y), d = __floats2half2_rn(l1.z, l1.w);
        uint4 w;
        w.x = *reinterpret_cast<const unsigned int*>(&a);
        w.y = *reinterpret_cast<const unsigned int*>(&b);
        w.z = *reinterpret_cast<const unsigned int*>(&c);
        w.w = *reinterpret_cast<const unsigned int*>(&d);
        LP[j] = w;
    }
}

// Two-level step, non-speculative: read f0, compare, read chosen child's feature.
__device__ __forceinline__ int step2(const int4 w, const int i,
                                     const float* __restrict__ x_s,
                                     const int xb, const int sz) {
    const float v0 = x_s[xb | ((w.x & 255) ^ sz)];
    const int   c0 = (v0 < __int_as_float(w.y)) ? 1 : 0;
    const int   fc = c0 ? ((w.x >> 16) & 255) : ((w.x >> 8) & 255);
    const float bc = c0 ? __int_as_float(w.w) : __int_as_float(w.z);
    const float vc = x_s[xb | (fc ^ sz)];
    const int   c1 = (vc < bc) ? 1 : 0;
    return 4 * i + 2 * c0 + c1;
}

// ===== Config A: 128 KB LDS (x 64K + full R3 table 64K), one block/CU, all
// 512 trees per block, no partials/sum. TA gathers per chain: R5, N7, LP = 3.
// R3 read becomes ds_read_b128: wave-uniform tree -> 8 distinct 16B recs
// spanning exactly 32 banks -> conflict-free.
__global__ __launch_bounds__(1024, 4)
void tree_traverse_big(const float* __restrict__ x,
                       const int*   __restrict__ root_nodes,
                       const float* __restrict__ root_biases,
                       const int4*  __restrict__ R1, const int4* __restrict__ R3g,
                       const int4*  __restrict__ R5, const int2* __restrict__ N7,
                       const uint4* __restrict__ LP,
                       float*       __restrict__ out)
{
    extern __shared__ float smem[];
    float* x_s = smem;                       // 16384 floats = 64 KB
    int4*  r3s = (int4*)(smem + 16384);      // 4096 recs   = 64 KB

    const int tid = threadIdx.x;
    const int s   = tid & 63;
    const int tg  = tid >> 6;                // wave id = tree-group
    const int s0  = blockIdx.x * 64;

    // ---- stage x rows (swizzled) + R3 table (coalesced b128) ----
    {
        const float4* xg = (const float4*)(x + (size_t)s0 * FF);
        const int r  = tid >> 4;
        const int v  = tid & 15;
        const int rz = r & 31;
        float* row = x_s + (r << 8);
        #pragma unroll
        for (int c = 0; c < 4; ++c) {
            const float4 q = xg[r * (FF / 4) + v + 16 * c];
            const int f0 = (v + 16 * c) * 4;
            row[(f0 + 0) ^ rz] = q.x;
            row[(f0 + 1) ^ rz] = q.y;
            row[(f0 + 2) ^ rz] = q.z;
            row[(f0 + 3) ^ rz] = q.w;
        }
        #pragma unroll
        for (int i = 0; i < NR3 / 1024; ++i)
            r3s[tid + i * 1024] = R3g[tid + i * 1024];
    }
    __syncthreads();

    const int xb = s << 8;
    const int sz = s & 31;
    float a0 = 0.f, a1 = 0.f, a2 = 0.f, a3 = 0.f;

    constexpr int TPT = TT / 16;   // 32 trees per thread
    constexpr int NP  = 8;
    constexpr int NJ  = TPT / NP;  // 4

    #pragma unroll 1
    for (int j = 0; j < NJ; ++j) {
        const int tbase = tg * TPT + j * NP;
        int p[NP];

        // ---- root + levels 1,2: scalar loads (wave-uniform), per-lane select ----
        #pragma unroll
        for (int k = 0; k < NP; ++k) {
            const int tu = __builtin_amdgcn_readfirstlane(tbase + k);
            const int   rn  = root_nodes[tu];
            const float rbv = root_biases[tu];
            const int4  rA  = R1[2 * tu];
            const int4  rB  = R1[2 * tu + 1];
            const int c0 = (x_s[xb | (rn ^ sz)] < rbv) ? 1 : 0;
            int4 r;
            r.x = c0 ? rB.x : rA.x;  r.y = c0 ? rB.y : rA.y;
            r.z = c0 ? rB.z : rA.z;  r.w = c0 ? rB.w : rA.w;
            p[k] = step2(r, c0, x_s, xb, sz);        // -> level-3 index [0,8)
        }
        // ---- levels 3+4 from LDS (ds_read_b128, conflict-free) ----
        #pragma unroll
        for (int k = 0; k < NP; ++k)
            p[k] = step2(r3s[((tbase + k) << 3) + p[k]], p[k], x_s, xb, sz);
        // ---- levels 5+6 (L2 gather 1) ----
        #pragma unroll
        for (int k = 0; k < NP; ++k)
            p[k] = step2(R5[((tbase + k) << 5) + p[k]], p[k], x_s, xb, sz);
        // ---- level 7 + leaf pair (L2 gathers 2+3, independent) ----
        #pragma unroll
        for (int k = 0; k < NP; ++k) {
            const int idx7 = ((tbase + k) << 7) + p[k];
            const int2  n  = N7[idx7];
            const uint4 lp = LP[idx7];
            const int c7 = (x_s[xb | (n.x ^ sz)] < __int_as_float(n.y)) ? 1 : 0;
            const unsigned int w01 = c7 ? lp.z : lp.x;
            const unsigned int w23 = c7 ? lp.w : lp.y;
            const float2 f01 = __half22float2(*reinterpret_cast<const __half2*>(&w01));
            const float2 f23 = __half22float2(*reinterpret_cast<const __half2*>(&w23));
            a0 += f01.x; a1 += f01.y; a2 += f23.x; a3 += f23.y;
        }
    }

    // ---- reduce 16 wave partials per sample (overlay on x_s), direct store ----
    __syncthreads();
    ((float4*)x_s)[tid] = make_float4(a0, a1, a2, a3);
    __syncthreads();
    if (tid < 256) {
        float o = 0.f;
        #pragma unroll
        for (int g = 0; g < 16; ++g)
            o += x_s[(g << 8) + tid];
        out[(size_t)s0 * 4 + tid] = o;
    }
}

// ===== Config B (proven R9 path): split halves, 64 KB LDS, partials + sum =====
__global__ __launch_bounds__(1024, 8)
void tree_traverse_kernel(const float* __restrict__ x,
                          const int*   __restrict__ root_nodes,
                          const float* __restrict__ root_biases,
                          const int4*  __restrict__ R1, const int4* __restrict__ R3,
                          const int4*  __restrict__ R5, const int2* __restrict__ N7,
                          const uint4* __restrict__ LP,
                          float*       __restrict__ part)
{
    extern __shared__ float x_s[];
    const int tid = threadIdx.x;
    const int s   = tid & 63;
    const int tg  = tid >> 6;
    const int s0  = blockIdx.x * 64;
    const int h0  = blockIdx.y * (TT / 2);
    {
        const float4* xg = (const float4*)(x + (size_t)s0 * FF);
        const int r = tid >> 4, v = tid & 15, rz = r & 31;
        float* row = x_s + (r << 8);
        #pragma unroll
        for (int c = 0; c < 4; ++c) {
            const float4 q = xg[r * (FF / 4) + v + 16 * c];
            const int f0 = (v + 16 * c) * 4;
            row[(f0 + 0) ^ rz] = q.x; row[(f0 + 1) ^ rz] = q.y;
            row[(f0 + 2) ^ rz] = q.z; row[(f0 + 3) ^ rz] = q.w;
        }
    }
    __syncthreads();
    const int xb = s << 8, sz = s & 31;
    float a0 = 0.f, a1 = 0.f, a2 = 0.f, a3 = 0.f;
    constexpr int TPT = (TT / 2) / 16, NP = 8, NJ = TPT / NP;
    #pragma unroll 1
    for (int j = 0; j < NJ; ++j) {
        const int tbase = h0 + tg * TPT + j * NP;
        int p[NP];
        #pragma unroll
        for (int k = 0; k < NP; ++k) {
            const int tu = __builtin_amdgcn_readfirstlane(tbase + k);
            const int   rn  = root_nodes[tu];
            const float rbv = root_biases[tu];
            const int4  rA  = R1[2 * tu];
            const int4  rB  = R1[2 * tu + 1];
            const int c0 = (x_s[xb | (rn ^ sz)] < rbv) ? 1 : 0;
            int4 r;
            r.x = c0 ? rB.x : rA.x;  r.y = c0 ? rB.y : rA.y;
            r.z = c0 ? rB.z : rA.z;  r.w = c0 ? rB.w : rA.w;
            p[k] = step2(r, c0, x_s, xb, sz);
        }
        #pragma unroll
        for (int k = 0; k < NP; ++k)
            p[k] = step2(R3[((tbase + k) << 3) + p[k]], p[k], x_s, xb, sz);
        #pragma unroll
        for (int k = 0; k < NP; ++k)
            p[k] = step2(R5[((tbase + k) << 5) + p[k]], p[k], x_s, xb, sz);
        #pragma unroll
        for (int k = 0; k < NP; ++k) {
            const int idx7 = ((tbase + k) << 7) + p[k];
            const int2  n  = N7[idx7];
            const uint4 lp = LP[idx7];
            const int c7 = (x_s[xb | (n.x ^ sz)] < __int_as_float(n.y)) ? 1 : 0;
            const unsigned int w01 = c7 ? lp.z : lp.x;
            const unsigned int w23 = c7 ? lp.w : lp.y;
            const float2 f01 = __half22float2(*reinterpret_cast<const __half2*>(&w01));
            const float2 f23 = __half22float2(*reinterpret_cast<const __half2*>(&w23));
            a0 += f01.x; a1 += f01.y; a2 += f23.x; a3 += f23.y;
        }
    }
    __syncthreads();
    ((float4*)x_s)[tid] = make_float4(a0, a1, a2, a3);
    __syncthreads();
    if (tid < 256) {
        float o = 0.f;
        #pragma unroll
        for (int g = 0; g < 16; ++g)
            o += x_s[(g << 8) + tid];
        part[((size_t)blockIdx.y * BB + s0) * 4 + tid] = o;
    }
}

__global__ void sum_kernel(const float4* __restrict__ part, float4* __restrict__ out) {
    const int i = blockIdx.x * 256 + threadIdx.x;
    if (i < BB) {
        const float4 a = part[i], b = part[BB + i];
        out[i] = make_float4(a.x + b.x, a.y + b.y, a.z + b.z, a.w + b.w);
    }
}

// Fallback (ws too small): direct traversal, known-correct.
__global__ __launch_bounds__(1024, 4)
void tree_traverse_fallback(const float* __restrict__ x,
                            const int* __restrict__ root_nodes,
                            const float* __restrict__ root_biases,
                            const int* __restrict__ nodes_flat,
                            const float* __restrict__ biases_flat,
                            const float* __restrict__ leaf_nodes,
                            float* __restrict__ out)
{
    extern __shared__ float x_s[];
    const int tid = threadIdx.x;
    const int s = tid & 63, tg = tid >> 6;
    const int s0 = blockIdx.x * 64;
    {
        const float4* xg = (const float4*)(x + (size_t)s0 * FF);
        const int r = tid >> 4, v = tid & 15, rz = r & 31;
        float* row = x_s + (r << 8);
        #pragma unroll
        for (int c = 0; c < 4; ++c) {
            const float4 q = xg[r * (FF / 4) + v + 16 * c];
            const int f0 = (v + 16 * c) * 4;
            row[(f0 + 0) ^ rz] = q.x; row[(f0 + 1) ^ rz] = q.y;
            row[(f0 + 2) ^ rz] = q.z; row[(f0 + 3) ^ rz] = q.w;
        }
    }
    __syncthreads();
    const int xb = s << 8, sz = s & 31;
    const float4* leaf4 = (const float4*)leaf_nodes;
    float a0 = 0.f, a1 = 0.f, a2 = 0.f, a3 = 0.f;
    #pragma unroll 1
    for (int j = 0; j < 4; ++j) {
        const int tbase = tg * 32 + j * 8;
        int p[8];
        #pragma unroll
        for (int k = 0; k < 8; ++k) {
            const int t = tbase + k;
            p[k] = 2 * t + ((x_s[xb | (root_nodes[t] ^ sz)] < root_biases[t]) ? 1 : 0);
        }
        #pragma unroll
        for (int l = 1; l <= DD; ++l) {
            #pragma unroll
            for (int k = 0; k < 8; ++k) {
                const int fi = nodes_flat[p[k]];
                const float bi = biases_flat[p[k]];
                const int c = (x_s[xb | (fi ^ sz)] < bi) ? 1 : 0;
                p[k] = 2 * p[k] + 2 * TT + c;
            }
        }
        #pragma unroll
        for (int k = 0; k < 8; ++k) {
            const float4 lf = leaf4[p[k] - 254 * TT];
            a0 += lf.x; a1 += lf.y; a2 += lf.z; a3 += lf.w;
        }
    }
    __syncthreads();
    ((float4*)x_s)[tid] = make_float4(a0, a1, a2, a3);
    __syncthreads();
    if (tid < 256) {
        float o = 0.f;
        #pragma unroll
        for (int g = 0; g < 16; ++g) o += x_s[(g << 8) + tid];
        out[(size_t)s0 * 4 + tid] = o;
    }
}

extern "C" void kernel_launch(void* const* d_in, const int* in_sizes, int n_in,
                              void* d_out, int out_size, void* d_ws, size_t ws_size,
                              hipStream_t stream) {
    const float* x           = (const float*)d_in[0];
    const int*   root_nodes  = (const int*)  d_in[1];
    const float* root_biases = (const float*)d_in[2];
    // d_in[3] = tree_indices = 2*t, folded into index math
    const int*   nodes_flat  = (const int*)  d_in[4];
    const float* biases_flat = (const float*)d_in[5];
    const float* leaf_nodes  = (const float*)d_in[6];
    float*       out         = (float*)d_out;

    constexpr size_t LDS_SMALL = 65536;
    constexpr size_t LDS_BIG   = 131072;

    if (ws_size >= WS_NEED) {
        char* ws = (char*)d_ws;
        int4*  R1 = (int4*)ws;
        int4*  R3 = (int4*)(ws + OFF_R3);
        int4*  R5 = (int4*)(ws + OFF_R5);
        int2*  N7 = (int2*)(ws + OFF_N7);
        uint4* LP = (uint4*)(ws + OFF_LP);
        float* part = (float*)(ws + OFF_PART);

        pack_kernel<<<(NTOT + 255) / 256, 256, 0, stream>>>(
            nodes_flat, biases_flat, (const float4*)leaf_nodes, R1, R3, R5, N7, LP);

        // Gate the 128 KB-LDS config on device capability + attribute success.
        int dev = 0;
        (void)hipGetDevice(&dev);
        int smCU = 0;
        (void)hipDeviceGetAttribute(&smCU,
                hipDeviceAttributeMaxSharedMemoryPerMultiprocessor, dev);
        bool big = false;
        if (smCU >= (int)LDS_BIG) {
            big = (hipFuncSetAttribute(
                       reinterpret_cast<const void*>(&tree_traverse_big),
                       hipFuncAttributeMaxDynamicSharedMemorySize,
                       (int)LDS_BIG) == hipSuccess);
        }

        if (big) {
            tree_traverse_big<<<BB / 64, 1024, LDS_BIG, stream>>>(
                x, root_nodes, root_biases, R1, R3, R5, N7, LP, out);
        } else {
            dim3 grid(BB / 64, 2);
            tree_traverse_kernel<<<grid, 1024, LDS_SMALL, stream>>>(
                x, root_nodes, root_biases, R1, R3, R5, N7, LP, part);
            sum_kernel<<<BB / 256, 256, 0, stream>>>((const float4*)part, (float4*)out);
        }
    } else {
        tree_traverse_fallback<<<BB / 64, 1024, LDS_SMALL, stream>>>(
            x, root_nodes, root_biases, nodes_flat, biases_flat, leaf_nodes, out);
    }
}

// Round 11
// 99.079 us; speedup vs baseline: 1.0448x; 1.0448x over previous
//
#include <hip/hip_runtime.h>
#include <hip/hip_fp16.h>

// B=16384 samples, F=256 features, T=512 trees, D=7 levels below root, C=4 outputs
#define BB 16384
#define FF 256
#define TT 512
#define DD 7

// Tables: R1 covers levels (1,2), R3 (3,4), R5 (5,6) as 16B two-level records;
// N7 = level-7 (feat,bias); LP = fp16x4 leaf PAIRS (16B) indexed by p7.
constexpr int NR1 = TT * 2;      // 1024
constexpr int NR3 = TT * 8;      // 4096 recs = 64 KB total; 16 KB per tree-quarter
constexpr int NR5 = TT * 32;     // 16384
constexpr int NN7 = TT * 128;    // 65536 (also LP count)
constexpr int NTOT = NR1 + NR3 + NR5 + NN7 + NN7;

constexpr size_t OFF_R3   = (size_t)NR1 * 16;
constexpr size_t OFF_R5   = OFF_R3 + (size_t)NR3 * 16;
constexpr size_t OFF_N7   = OFF_R5 + (size_t)NR5 * 16;
constexpr size_t OFF_LP   = OFF_N7 + (size_t)NN7 * 8;
constexpr size_t OFF_PART = OFF_LP + (size_t)NN7 * 16;
constexpr size_t WS_NEED  = OFF_PART + (size_t)4 * BB * 4 * sizeof(float);

__global__ void pack_kernel(const int* __restrict__ nf, const float* __restrict__ bf,
                            const float4* __restrict__ leaf4,
                            int4* __restrict__ R1, int4* __restrict__ R3,
                            int4* __restrict__ R5, int2* __restrict__ N7,
                            uint4* __restrict__ LP) {
    const int i = blockIdx.x * 256 + threadIdx.x;
    if (i < NR1) {                       // level-1 node i; level-2 children 2i,2i+1
        const int e0 = i, eC = 2 * TT + 2 * i;
        const int fp = (nf[e0] & 255) | ((nf[eC] & 255) << 8) | ((nf[eC + 1] & 255) << 16);
        R1[i] = make_int4(fp, __float_as_int(bf[e0]),
                          __float_as_int(bf[eC]), __float_as_int(bf[eC + 1]));
    } else if (i < NR1 + NR3) {
        const int r = i - NR1;
        const int e0 = 6 * TT + r, eC = 14 * TT + 2 * r;
        const int fp = (nf[e0] & 255) | ((nf[eC] & 255) << 8) | ((nf[eC + 1] & 255) << 16);
        R3[r] = make_int4(fp, __float_as_int(bf[e0]),
                          __float_as_int(bf[eC]), __float_as_int(bf[eC + 1]));
    } else if (i < NR1 + NR3 + NR5) {
        const int r = i - NR1 - NR3;
        const int e0 = 30 * TT + r, eC = 62 * TT + 2 * r;
        const int fp = (nf[e0] & 255) | ((nf[eC] & 255) << 8) | ((nf[eC + 1] & 255) << 16);
        R5[r] = make_int4(fp, __float_as_int(bf[e0]),
                          __float_as_int(bf[eC]), __float_as_int(bf[eC + 1]));
    } else if (i < NR1 + NR3 + NR5 + NN7) {
        const int r = i - NR1 - NR3 - NR5;
        const int e = 126 * TT + r;
        N7[r] = make_int2(nf[e] & 255, __float_as_int(bf[e]));
    } else if (i < NTOT) {
        const int j = i - NR1 - NR3 - NR5 - NN7;   // leaf-pair id: leaves 2j, 2j+1
        const float4 l0 = leaf4[2 * j], l1 = leaf4[2 * j + 1];
        const __half2 a = __floats2half2_rn(l0.x, l0.y), b = __floats2half2_rn(l0.z, l0.w);
        const __half2 c = __floats2half2_rn(l1.x, l1.y), d = __floats2half2_rn(l1.z, l1.w);
        uint4 w;
        w.x = *reinterpret_cast<const unsigned int*>(&a);
        w.y = *reinterpret_cast<const unsigned int*>(&b);
        w.z = *reinterpret_cast<const unsigned int*>(&c);
        w.w = *reinterpret_cast<const unsigned int*>(&d);
        LP[j] = w;
    }
}

// Two-level step, non-speculative: read f0, compare, read chosen child's feature.
__device__ __forceinline__ int step2(const int4 w, const int i,
                                     const float* __restrict__ x_s,
                                     const int xb, const int sz) {
    const float v0 = x_s[xb | ((w.x & 255) ^ sz)];
    const int   c0 = (v0 < __int_as_float(w.y)) ? 1 : 0;
    const int   fc = c0 ? ((w.x >> 16) & 255) : ((w.x >> 8) & 255);
    const float bc = c0 ? __int_as_float(w.w) : __int_as_float(w.z);
    const float vc = x_s[xb | (fc ^ sz)];
    const int   c1 = (vc < bc) ? 1 : 0;
    return 4 * i + 2 * c0 + c1;
}

// ===== Config Q: tree-QUARTER blocks. LDS = x 64K + R3 quarter slice 16K =
// 80 KB exactly -> 2 blocks/CU = 32 waves/CU (full occupancy) AND only 3
// vector gathers per chain (R5, N7, LP) — the combination R10's 128 KB
// config couldn't reach. Grid (256,4); partials summed by sum_kernel.
__global__ __launch_bounds__(1024, 8)
void tree_traverse_q(const float* __restrict__ x,
                     const int*   __restrict__ root_nodes,
                     const float* __restrict__ root_biases,
                     const int4*  __restrict__ R1, const int4* __restrict__ R3g,
                     const int4*  __restrict__ R5, const int2* __restrict__ N7,
                     const uint4* __restrict__ LP,
                     float*       __restrict__ part)
{
    extern __shared__ float smem[];
    float* x_s = smem;                       // 16384 floats = 64 KB
    int4*  r3s = (int4*)(smem + 16384);      // 1024 recs   = 16 KB

    const int tid = threadIdx.x;
    const int s   = tid & 63;
    const int tg  = tid >> 6;                // wave id = tree-group (16)
    const int s0  = blockIdx.x * 64;
    const int q   = blockIdx.y;              // tree quarter
    const int h0  = q * (TT / 4);            // 128 trees per block

    // ---- stage x rows (swizzled) + R3 quarter slice (1 int4 per thread) ----
    {
        const float4* xg = (const float4*)(x + (size_t)s0 * FF);
        const int r  = tid >> 4;
        const int v  = tid & 15;
        const int rz = r & 31;
        float* row = x_s + (r << 8);
        #pragma unroll
        for (int c = 0; c < 4; ++c) {
            const float4 qv = xg[r * (FF / 4) + v + 16 * c];
            const int f0 = (v + 16 * c) * 4;
            row[(f0 + 0) ^ rz] = qv.x;
            row[(f0 + 1) ^ rz] = qv.y;
            row[(f0 + 2) ^ rz] = qv.z;
            row[(f0 + 3) ^ rz] = qv.w;
        }
        r3s[tid] = R3g[(q << 10) + tid];     // trees [h0,h0+128) -> recs [q*1024, +1024)
    }
    __syncthreads();

    const int xb = s << 8;
    const int sz = s & 31;
    float a0 = 0.f, a1 = 0.f, a2 = 0.f, a3 = 0.f;

    constexpr int NP = 8;                    // 8 trees per thread, single pass
    const int lt0 = tg * NP;                 // local tree base within quarter
    int p[NP];

    // ---- root + levels 1,2: scalar loads (wave-uniform), per-lane select ----
    #pragma unroll
    for (int k = 0; k < NP; ++k) {
        const int tu = __builtin_amdgcn_readfirstlane(h0 + lt0 + k);
        const int   rn  = root_nodes[tu];
        const float rbv = root_biases[tu];
        const int4  rA  = R1[2 * tu];
        const int4  rB  = R1[2 * tu + 1];
        const int c0 = (x_s[xb | (rn ^ sz)] < rbv) ? 1 : 0;
        int4 r;
        r.x = c0 ? rB.x : rA.x;  r.y = c0 ? rB.y : rA.y;
        r.z = c0 ? rB.z : rA.z;  r.w = c0 ? rB.w : rA.w;
        p[k] = step2(r, c0, x_s, xb, sz);    // -> level-3 index [0,8)
    }
    // ---- levels 3+4 from LDS slice (local tree index) ----
    #pragma unroll
    for (int k = 0; k < NP; ++k)
        p[k] = step2(r3s[((lt0 + k) << 3) + p[k]], p[k], x_s, xb, sz);
    // ---- levels 5+6 (L2 gather 1) ----
    #pragma unroll
    for (int k = 0; k < NP; ++k)
        p[k] = step2(R5[((h0 + lt0 + k) << 5) + p[k]], p[k], x_s, xb, sz);
    // ---- level 7 + leaf pair (L2 gathers 2+3, independent) ----
    #pragma unroll
    for (int k = 0; k < NP; ++k) {
        const int idx7 = ((h0 + lt0 + k) << 7) + p[k];
        const int2  n  = N7[idx7];
        const uint4 lp = LP[idx7];
        const int c7 = (x_s[xb | (n.x ^ sz)] < __int_as_float(n.y)) ? 1 : 0;
        const unsigned int w01 = c7 ? lp.z : lp.x;
        const unsigned int w23 = c7 ? lp.w : lp.y;
        const float2 f01 = __half22float2(*reinterpret_cast<const __half2*>(&w01));
        const float2 f23 = __half22float2(*reinterpret_cast<const __half2*>(&w23));
        a0 += f01.x; a1 += f01.y; a2 += f23.x; a3 += f23.y;
    }

    // ---- reduce 16 wave partials per sample (overlay on x_s) ----
    __syncthreads();
    ((float4*)x_s)[tid] = make_float4(a0, a1, a2, a3);
    __syncthreads();
    if (tid < 256) {
        float o = 0.f;
        #pragma unroll
        for (int g = 0; g < 16; ++g)
            o += x_s[(g << 8) + tid];
        part[((size_t)q * BB + s0) * 4 + tid] = o;    // coalesced 1 KB
    }
}

__global__ void sum_kernel(const float4* __restrict__ part, float4* __restrict__ out,
                           int nparts) {
    const int i = blockIdx.x * 256 + threadIdx.x;
    if (i < BB) {
        float4 o = part[i];
        for (int q = 1; q < nparts; ++q) {
            const float4 a = part[(size_t)q * BB + i];
            o.x += a.x; o.y += a.y; o.z += a.z; o.w += a.w;
        }
        out[i] = o;
    }
}

// ===== Config B (proven R9 path): tree-half blocks, 64 KB LDS =====
__global__ __launch_bounds__(1024, 8)
void tree_traverse_kernel(const float* __restrict__ x,
                          const int*   __restrict__ root_nodes,
                          const float* __restrict__ root_biases,
                          const int4*  __restrict__ R1, const int4* __restrict__ R3,
                          const int4*  __restrict__ R5, const int2* __restrict__ N7,
                          const uint4* __restrict__ LP,
                          float*       __restrict__ part)
{
    extern __shared__ float x_s[];
    const int tid = threadIdx.x;
    const int s   = tid & 63;
    const int tg  = tid >> 6;
    const int s0  = blockIdx.x * 64;
    const int h0  = blockIdx.y * (TT / 2);
    {
        const float4* xg = (const float4*)(x + (size_t)s0 * FF);
        const int r = tid >> 4, v = tid & 15, rz = r & 31;
        float* row = x_s + (r << 8);
        #pragma unroll
        for (int c = 0; c < 4; ++c) {
            const float4 q = xg[r * (FF / 4) + v + 16 * c];
            const int f0 = (v + 16 * c) * 4;
            row[(f0 + 0) ^ rz] = q.x; row[(f0 + 1) ^ rz] = q.y;
            row[(f0 + 2) ^ rz] = q.z; row[(f0 + 3) ^ rz] = q.w;
        }
    }
    __syncthreads();
    const int xb = s << 8, sz = s & 31;
    float a0 = 0.f, a1 = 0.f, a2 = 0.f, a3 = 0.f;
    constexpr int TPT = (TT / 2) / 16, NP = 8, NJ = TPT / NP;
    #pragma unroll 1
    for (int j = 0; j < NJ; ++j) {
        const int tbase = h0 + tg * TPT + j * NP;
        int p[NP];
        #pragma unroll
        for (int k = 0; k < NP; ++k) {
            const int tu = __builtin_amdgcn_readfirstlane(tbase + k);
            const int   rn  = root_nodes[tu];
            const float rbv = root_biases[tu];
            const int4  rA  = R1[2 * tu];
            const int4  rB  = R1[2 * tu + 1];
            const int c0 = (x_s[xb | (rn ^ sz)] < rbv) ? 1 : 0;
            int4 r;
            r.x = c0 ? rB.x : rA.x;  r.y = c0 ? rB.y : rA.y;
            r.z = c0 ? rB.z : rA.z;  r.w = c0 ? rB.w : rA.w;
            p[k] = step2(r, c0, x_s, xb, sz);
        }
        #pragma unroll
        for (int k = 0; k < NP; ++k)
            p[k] = step2(R3[((tbase + k) << 3) + p[k]], p[k], x_s, xb, sz);
        #pragma unroll
        for (int k = 0; k < NP; ++k)
            p[k] = step2(R5[((tbase + k) << 5) + p[k]], p[k], x_s, xb, sz);
        #pragma unroll
        for (int k = 0; k < NP; ++k) {
            const int idx7 = ((tbase + k) << 7) + p[k];
            const int2  n  = N7[idx7];
            const uint4 lp = LP[idx7];
            const int c7 = (x_s[xb | (n.x ^ sz)] < __int_as_float(n.y)) ? 1 : 0;
            const unsigned int w01 = c7 ? lp.z : lp.x;
            const unsigned int w23 = c7 ? lp.w : lp.y;
            const float2 f01 = __half22float2(*reinterpret_cast<const __half2*>(&w01));
            const float2 f23 = __half22float2(*reinterpret_cast<const __half2*>(&w23));
            a0 += f01.x; a1 += f01.y; a2 += f23.x; a3 += f23.y;
        }
    }
    __syncthreads();
    ((float4*)x_s)[tid] = make_float4(a0, a1, a2, a3);
    __syncthreads();
    if (tid < 256) {
        float o = 0.f;
        #pragma unroll
        for (int g = 0; g < 16; ++g)
            o += x_s[(g << 8) + tid];
        part[((size_t)blockIdx.y * BB + s0) * 4 + tid] = o;
    }
}

// Fallback (ws too small): direct traversal, known-correct.
__global__ __launch_bounds__(1024, 4)
void tree_traverse_fallback(const float* __restrict__ x,
                            const int* __restrict__ root_nodes,
                            const float* __restrict__ root_biases,
                            const int* __restrict__ nodes_flat,
                            const float* __restrict__ biases_flat,
                            const float* __restrict__ leaf_nodes,
                            float* __restrict__ out)
{
    extern __shared__ float x_s[];
    const int tid = threadIdx.x;
    const int s = tid & 63, tg = tid >> 6;
    const int s0 = blockIdx.x * 64;
    {
        const float4* xg = (const float4*)(x + (size_t)s0 * FF);
        const int r = tid >> 4, v = tid & 15, rz = r & 31;
        float* row = x_s + (r << 8);
        #pragma unroll
        for (int c = 0; c < 4; ++c) {
            const float4 q = xg[r * (FF / 4) + v + 16 * c];
            const int f0 = (v + 16 * c) * 4;
            row[(f0 + 0) ^ rz] = q.x; row[(f0 + 1) ^ rz] = q.y;
            row[(f0 + 2) ^ rz] = q.z; row[(f0 + 3) ^ rz] = q.w;
        }
    }
    __syncthreads();
    const int xb = s << 8, sz = s & 31;
    const float4* leaf4 = (const float4*)leaf_nodes;
    float a0 = 0.f, a1 = 0.f, a2 = 0.f, a3 = 0.f;
    #pragma unroll 1
    for (int j = 0; j < 4; ++j) {
        const int tbase = tg * 32 + j * 8;
        int p[8];
        #pragma unroll
        for (int k = 0; k < 8; ++k) {
            const int t = tbase + k;
            p[k] = 2 * t + ((x_s[xb | (root_nodes[t] ^ sz)] < root_biases[t]) ? 1 : 0);
        }
        #pragma unroll
        for (int l = 1; l <= DD; ++l) {
            #pragma unroll
            for (int k = 0; k < 8; ++k) {
                const int fi = nodes_flat[p[k]];
                const float bi = biases_flat[p[k]];
                const int c = (x_s[xb | (fi ^ sz)] < bi) ? 1 : 0;
                p[k] = 2 * p[k] + 2 * TT + c;
            }
        }
        #pragma unroll
        for (int k = 0; k < 8; ++k) {
            const float4 lf = leaf4[p[k] - 254 * TT];
            a0 += lf.x; a1 += lf.y; a2 += lf.z; a3 += lf.w;
        }
    }
    __syncthreads();
    ((float4*)x_s)[tid] = make_float4(a0, a1, a2, a3);
    __syncthreads();
    if (tid < 256) {
        float o = 0.f;
        #pragma unroll
        for (int g = 0; g < 16; ++g) o += x_s[(g << 8) + tid];
        out[(size_t)s0 * 4 + tid] = o;
    }
}

extern "C" void kernel_launch(void* const* d_in, const int* in_sizes, int n_in,
                              void* d_out, int out_size, void* d_ws, size_t ws_size,
                              hipStream_t stream) {
    const float* x           = (const float*)d_in[0];
    const int*   root_nodes  = (const int*)  d_in[1];
    const float* root_biases = (const float*)d_in[2];
    // d_in[3] = tree_indices = 2*t, folded into index math
    const int*   nodes_flat  = (const int*)  d_in[4];
    const float* biases_flat = (const float*)d_in[5];
    const float* leaf_nodes  = (const float*)d_in[6];
    float*       out         = (float*)d_out;

    constexpr size_t LDS_SMALL = 65536;
    constexpr size_t LDS_Q     = 65536 + 16384;   // 81920: x + R3 quarter slice

    if (ws_size >= WS_NEED) {
        char* ws = (char*)d_ws;
        int4*  R1 = (int4*)ws;
        int4*  R3 = (int4*)(ws + OFF_R3);
        int4*  R5 = (int4*)(ws + OFF_R5);
        int2*  N7 = (int2*)(ws + OFF_N7);
        uint4* LP = (uint4*)(ws + OFF_LP);
        float* part = (float*)(ws + OFF_PART);

        pack_kernel<<<(NTOT + 255) / 256, 256, 0, stream>>>(
            nodes_flat, biases_flat, (const float4*)leaf_nodes, R1, R3, R5, N7, LP);

        // Gate the 80 KB-LDS quarter config (R1 proved >64 KB dynamic LDS works).
        int dev = 0;
        (void)hipGetDevice(&dev);
        int smCU = 0;
        (void)hipDeviceGetAttribute(&smCU,
                hipDeviceAttributeMaxSharedMemoryPerMultiprocessor, dev);
        bool qok = false;
        if (smCU >= (int)(2 * LDS_Q)) {
            qok = (hipFuncSetAttribute(
                       reinterpret_cast<const void*>(&tree_traverse_q),
                       hipFuncAttributeMaxDynamicSharedMemorySize,
                       (int)LDS_Q) == hipSuccess);
        }

        if (qok) {
            dim3 grid(BB / 64, 4);
            tree_traverse_q<<<grid, 1024, LDS_Q, stream>>>(
                x, root_nodes, root_biases, R1, R3, R5, N7, LP, part);
            sum_kernel<<<BB / 256, 256, 0, stream>>>((const float4*)part, (float4*)out, 4);
        } else {
            dim3 grid(BB / 64, 2);
            tree_traverse_kernel<<<grid, 1024, LDS_SMALL, stream>>>(
                x, root_nodes, root_biases, R1, R3, R5, N7, LP, part);
            sum_kernel<<<BB / 256, 256, 0, stream>>>((const float4*)part, (float4*)out, 2);
        }
    } else {
        tree_traverse_fallback<<<BB / 64, 1024, LDS_SMALL, stream>>>(
            x, root_nodes, root_biases, nodes_flat, biases_flat, leaf_nodes, out);
    }
}